// Round 3
// baseline (319.382 us; speedup 1.0000x reference)
//
#include <hip/hip_runtime.h>
#include <cmath>

typedef _Float16 half8 __attribute__((ext_vector_type(8)));
typedef _Float16 half4 __attribute__((ext_vector_type(4)));
typedef float floatx4 __attribute__((ext_vector_type(4)));

// Direct global->LDS DMA, 16B per lane. LDS dest = uniform base + lane*16.
__device__ __forceinline__ void load_lds16(const void* g, void* l) {
  __builtin_amdgcn_global_load_lds((const __attribute__((address_space(1))) void*)g,
                                   (__attribute__((address_space(3))) void*)l, 16, 0, 0);
}

// ---------------- prep: cast X fp32 -> fp16 ----------------
__global__ void cast_x_kernel(const float* __restrict__ x, _Float16* __restrict__ xh, int n4) {
  int i = blockIdx.x * blockDim.x + threadIdx.x;
  if (i < n4) {
    float4 v = ((const float4*)x)[i];
    half4 h;
    h[0] = (_Float16)v.x; h[1] = (_Float16)v.y; h[2] = (_Float16)v.z; h[3] = (_Float16)v.w;
    ((half4*)xh)[i] = h;
  }
}

// ---------------- prep: W[k][n] fp32 -> Wt[n][k] fp16 (combined Q|K|V) ----------------
__global__ void wt_kernel(const float* __restrict__ Wq, const float* __restrict__ Wk,
                          const float* __restrict__ Wv, _Float16* __restrict__ Wt) {
  __shared__ float tile[32][33];
  int n0 = blockIdx.x * 32, k0 = blockIdx.y * 32, w = blockIdx.z;
  const float* src = (w == 0) ? Wq : (w == 1) ? Wk : Wv;
  int c = threadIdx.x & 31, r8 = threadIdx.x >> 5;
  for (int p = 0; p < 4; ++p) {
    int r = p * 8 + r8;
    tile[r][c] = src[(size_t)(k0 + r) * 1024 + n0 + c];
  }
  __syncthreads();
  for (int p = 0; p < 4; ++p) {
    int rr = p * 8 + r8;  // n within tile
    Wt[(size_t)(w * 1024 + n0 + rr) * 1024 + k0 + c] = (_Float16)tile[c][rr];
  }
}

// ---------------- V[t][d] -> Vt[d][t] fp16 ----------------
__global__ void vt_kernel(const _Float16* __restrict__ V, _Float16* __restrict__ Vt) {
  __shared__ _Float16 tile[32][33];
  int t0 = blockIdx.x * 32, d0 = blockIdx.y * 32, b = blockIdx.z;
  const _Float16* Vb = V + (size_t)b * 2048 * 1024;
  _Float16* Vtb = Vt + (size_t)b * 1024 * 2048;
  int c = threadIdx.x & 31, r8 = threadIdx.x >> 5;
  for (int p = 0; p < 4; ++p) {
    int r = p * 8 + r8;
    tile[r][c] = Vb[(size_t)(t0 + r) * 1024 + d0 + c];
  }
  __syncthreads();
  for (int p = 0; p < 4; ++p) {
    int rr = p * 8 + r8;  // d within tile
    Vtb[(size_t)(d0 + rr) * 2048 + t0 + c] = tile[c][rr];
  }
}

// ---------------- shared GEMM core: C128x128 += A[m][k] * B[n][k]^T ----------------
// A: row-major [M][lda] (k contiguous), B: row-major [N][ldb] (k contiguous).
// 256 threads = 4 waves in 2x2; each wave 64x64 via 4x4 of 16x16x32 MFMA.
// LDS layout is MFMA-NATIVE: 8 tiles of 1KB per operand; tile t holds rows
// [t*16, t*16+16) x 32 halves, chunk c (16B) = (row = t*16 + (c&15), k16 = c>>4).
// Fragment read = tile_base + lane*16B: 64 consecutive chunks -> provably
// conflict-free (same pattern as the DMA write). Permutation is absorbed into
// the per-lane GLOBAL source addresses of global_load_lds (same 64B-line set
// per instruction as row-major -> coalescing unchanged).
__device__ __forceinline__ void gemm_core(const _Float16* __restrict__ A, int lda, int m0,
                                          const _Float16* __restrict__ B, int ldb, int n0,
                                          int kIters, _Float16* sA, _Float16* sB,
                                          floatx4 acc[4][4]) {
  int tid = threadIdx.x;
  int lane = tid & 63, wave = tid >> 6;
  int wm = (wave >> 1) << 6, wn = (wave & 1) << 6;

  // Each wave stages chunks [wave*128, wave*128+128) per operand via 2 DMAs.
  int c0 = wave * 128 + lane;
  int c1 = c0 + 64;
  // chunk -> (row, k16) under MFMA-native tiling
  int r0 = ((c0 >> 6) << 4) + (c0 & 15), k16_0 = (c0 >> 4) & 3;
  int r1 = ((c1 >> 6) << 4) + (c1 & 15), k16_1 = (c1 >> 4) & 3;
  const _Float16* gA0 = A + (size_t)(m0 + r0) * lda + k16_0 * 8;
  const _Float16* gA1 = A + (size_t)(m0 + r1) * lda + k16_1 * 8;
  const _Float16* gB0 = B + (size_t)(n0 + r0) * ldb + k16_0 * 8;
  const _Float16* gB1 = B + (size_t)(n0 + r1) * ldb + k16_1 * 8;
  _Float16* lA0 = sA + wave * 1024;  // wave-uniform dest; HW adds lane*16B
  _Float16* lA1 = lA0 + 512;
  _Float16* lB0 = sB + wave * 1024;
  _Float16* lB1 = lB0 + 512;

  int ta = wm >> 4, tb = wn >> 4;  // fragment tile bases
  int lo = lane * 8;               // halves

  for (int kt = 0; kt < kIters; ++kt) {
    int kb = kt << 5;  // halves
    __syncthreads();
    load_lds16(gA0 + kb, lA0);
    load_lds16(gA1 + kb, lA1);
    load_lds16(gB0 + kb, lB0);
    load_lds16(gB1 + kb, lB1);
    __syncthreads();  // compiler emits s_waitcnt vmcnt(0) before s_barrier
    half8 af[4], bf[4];
    for (int i = 0; i < 4; ++i) af[i] = *(const half8*)(sA + (ta + i) * 512 + lo);
    for (int j = 0; j < 4; ++j) bf[j] = *(const half8*)(sB + (tb + j) * 512 + lo);
    for (int i = 0; i < 4; ++i)
      for (int j = 0; j < 4; ++j)
        acc[i][j] = __builtin_amdgcn_mfma_f32_16x16x32_f16(af[i], bf[j], acc[i][j], 0, 0, 0);
  }
}

// ---------------- QKV projection: [8192x1024] x [3072x1024]^T ----------------
__global__ void qkv_kernel(const _Float16* __restrict__ X, const _Float16* __restrict__ Wt,
                           _Float16* __restrict__ Q, _Float16* __restrict__ K,
                           _Float16* __restrict__ Vv) {
  __shared__ __align__(16) _Float16 sA[4096];
  __shared__ __align__(16) _Float16 sB[4096];
  floatx4 acc[4][4];
  for (int i = 0; i < 4; ++i)
    for (int j = 0; j < 4; ++j) acc[i][j] = (floatx4){0.f, 0.f, 0.f, 0.f};
  int m0 = blockIdx.y * 128, n0 = blockIdx.x * 128;
  gemm_core(X, 1024, m0, Wt, 1024, n0, 32, sA, sB, acc);
  int lane = threadIdx.x & 63, wave = threadIdx.x >> 6;
  int wm = (wave >> 1) << 6, wn = (wave & 1) << 6;
  int quad = lane >> 4, cl = lane & 15;
  int which = n0 >> 10;  // whole block maps to one of Q/K/V (128 | 1024)
  _Float16* dst = (which == 0) ? Q : (which == 1) ? K : Vv;
  int colbase = (n0 & 1023) + wn;
  for (int i = 0; i < 4; ++i)
    for (int j = 0; j < 4; ++j)
      for (int rr = 0; rr < 4; ++rr) {
        int row = m0 + wm + i * 16 + quad * 4 + rr;
        int col = colbase + j * 16 + cl;
        dst[(size_t)row * 1024 + col] = (_Float16)acc[i][j][rr];
      }
}

// ---------------- scores: S[t][s] = Q.K^T / 32, lower-triangular tiles only ----------------
__global__ void qk_kernel(const _Float16* __restrict__ Q, const _Float16* __restrict__ K,
                          _Float16* __restrict__ S) {
  __shared__ __align__(16) _Float16 sA[4096];
  __shared__ __align__(16) _Float16 sB[4096];
  int p = blockIdx.x, b = blockIdx.y;
  int ti = 0;
  while ((ti + 1) * (ti + 2) / 2 <= p) ++ti;
  int tj = p - ti * (ti + 1) / 2;
  const _Float16* Qb = Q + (size_t)b * 2048 * 1024;
  const _Float16* Kb = K + (size_t)b * 2048 * 1024;
  _Float16* Sb = S + (size_t)b * 2048 * 2048;
  floatx4 acc[4][4];
  for (int i = 0; i < 4; ++i)
    for (int j = 0; j < 4; ++j) acc[i][j] = (floatx4){0.f, 0.f, 0.f, 0.f};
  gemm_core(Qb, 1024, ti * 128, Kb, 1024, tj * 128, 32, sA, sB, acc);
  int lane = threadIdx.x & 63, wave = threadIdx.x >> 6;
  int wm = (wave >> 1) << 6, wn = (wave & 1) << 6;
  int quad = lane >> 4, cl = lane & 15;
  for (int i = 0; i < 4; ++i)
    for (int j = 0; j < 4; ++j)
      for (int rr = 0; rr < 4; ++rr) {
        int row = ti * 128 + wm + i * 16 + quad * 4 + rr;
        int col = tj * 128 + wn + j * 16 + cl;
        float val = acc[i][j][rr] * 0.03125f;  // 1/sqrt(1024)
        if (col > row) val = -INFINITY;        // causal mask (diagonal tiles)
        Sb[(size_t)row * 2048 + col] = (_Float16)val;
      }
}

// ---------------- row softmax in place (fp16 S -> fp16 P) ----------------
__global__ void softmax_kernel(_Float16* __restrict__ S) {
  __shared__ float srow[2048];
  __shared__ float redm[4];
  __shared__ float reds[4];
  int idx = blockIdx.x;
  int b = idx >> 11, t = idx & 2047;
  _Float16* row = S + ((size_t)b * 2048 + t) * 2048;
  int rowlen = ((t >> 7) + 1) << 7;  // tile-aligned valid length
  int nch = rowlen >> 3;
  int tid = threadIdx.x;
  int lane = tid & 63, wv = tid >> 6;
  float mx = -INFINITY;
  for (int c = tid; c < nch; c += 256) {
    half8 h = *(const half8*)(row + c * 8);
    for (int e = 0; e < 8; ++e) {
      float f = (float)h[e];
      srow[c * 8 + e] = f;
      mx = fmaxf(mx, f);
    }
  }
  for (int o = 32; o; o >>= 1) mx = fmaxf(mx, __shfl_down(mx, o, 64));
  if (lane == 0) redm[wv] = mx;
  __syncthreads();
  mx = fmaxf(fmaxf(redm[0], redm[1]), fmaxf(redm[2], redm[3]));
  float sum = 0.f;
  for (int c = tid; c < nch; c += 256) {
    for (int e = 0; e < 8; ++e) {
      float ev = __expf(srow[c * 8 + e] - mx);  // exp(-inf)=0 handles mask
      srow[c * 8 + e] = ev;
      sum += ev;
    }
  }
  for (int o = 32; o; o >>= 1) sum += __shfl_down(sum, o, 64);
  if (lane == 0) reds[wv] = sum;
  __syncthreads();
  sum = reds[0] + reds[1] + reds[2] + reds[3];
  float inv = 1.0f / sum;
  for (int c = tid; c < nch; c += 256) {
    half8 h;
    for (int e = 0; e < 8; ++e) h[e] = (_Float16)(srow[c * 8 + e] * inv);
    *(half8*)(row + c * 8) = h;
  }
}

// ---------------- O = P.V : [2048x(kmax)] x [1024x2048]^T, fp32 out ----------------
// blockIdx.y remapped so consecutive block pairs (ti, 15-ti) sum to a constant
// 68 K-iters -> no straggler tail (was: ti=15 block did 16x ti=0's work).
__global__ void pv_kernel(const _Float16* __restrict__ P, const _Float16* __restrict__ Vt,
                          float* __restrict__ out) {
  __shared__ __align__(16) _Float16 sA[4096];
  __shared__ __align__(16) _Float16 sB[4096];
  int n0 = blockIdx.x * 128, b = blockIdx.z;
  int y = blockIdx.y;
  int ti = (y & 1) ? (15 - (y >> 1)) : (y >> 1);
  const _Float16* Pb = P + (size_t)b * 2048 * 2048;
  const _Float16* Vb = Vt + (size_t)b * 1024 * 2048;
  floatx4 acc[4][4];
  for (int i = 0; i < 4; ++i)
    for (int j = 0; j < 4; ++j) acc[i][j] = (floatx4){0.f, 0.f, 0.f, 0.f};
  gemm_core(Pb, 2048, ti * 128, Vb, 2048, n0, (ti + 1) * 4, sA, sB, acc);  // causal k-limit
  int lane = threadIdx.x & 63, wave = threadIdx.x >> 6;
  int wm = (wave >> 1) << 6, wn = (wave & 1) << 6;
  int quad = lane >> 4, cl = lane & 15;
  for (int i = 0; i < 4; ++i)
    for (int j = 0; j < 4; ++j)
      for (int rr = 0; rr < 4; ++rr) {
        int row = ti * 128 + wm + i * 16 + quad * 4 + rr;  // t
        int col = n0 + wn + j * 16 + cl;                   // d
        float v = acc[i][j][rr];
        out[((size_t)b * 2048 + row) * 1024 + col] = rintf(v * 10000.f) * 1e-4f;
      }
}

extern "C" void kernel_launch(void* const* d_in, const int* in_sizes, int n_in,
                              void* d_out, int out_size, void* d_ws, size_t ws_size,
                              hipStream_t stream) {
  const float* emb = (const float*)d_in[0];
  const float* Wk = (const float*)d_in[1];
  const float* Wq = (const float*)d_in[2];
  const float* Wv = (const float*)d_in[3];
  float* out = (float*)d_out;

  _Float16* ws = (_Float16*)d_ws;
  _Float16* Xh = ws;                         // 8M halves
  _Float16* Wt = Xh + (size_t)8192 * 1024;   // 3M
  _Float16* Q  = Wt + (size_t)3072 * 1024;   // 8M
  _Float16* K  = Q  + (size_t)8192 * 1024;   // 8M
  _Float16* V  = K  + (size_t)8192 * 1024;   // 8M
  _Float16* Vt = V  + (size_t)8192 * 1024;   // 8M
  _Float16* S  = Vt + (size_t)8192 * 1024;   // 16M  (total 59M halves = 118 MB)

  cast_x_kernel<<<8192, 256, 0, stream>>>(emb, Xh, 2097152);
  wt_kernel<<<dim3(32, 32, 3), 256, 0, stream>>>(Wq, Wk, Wv, Wt);
  qkv_kernel<<<dim3(24, 64), 256, 0, stream>>>(Xh, Wt, Q, K, V);
  vt_kernel<<<dim3(64, 32, 4), 256, 0, stream>>>(V, Vt);
  qk_kernel<<<dim3(136, 4), 256, 0, stream>>>(Q, K, S);
  softmax_kernel<<<8192, 256, 0, stream>>>(S);
  pv_kernel<<<dim3(8, 16, 4), 256, 0, stream>>>(S, Vt, out);
}

// Round 4
// 260.025 us; speedup vs baseline: 1.2283x; 1.2283x over previous
//
#include <hip/hip_runtime.h>
#include <cmath>

typedef _Float16 half8 __attribute__((ext_vector_type(8)));
typedef _Float16 half4 __attribute__((ext_vector_type(4)));
typedef float floatx4 __attribute__((ext_vector_type(4)));

// Direct global->LDS DMA, 16B per lane. Per-lane global src; LDS dest =
// wave-uniform base + lane*16.
__device__ __forceinline__ void load_lds16(const void* g, void* l) {
  __builtin_amdgcn_global_load_lds((const __attribute__((address_space(1))) void*)g,
                                   (__attribute__((address_space(3))) void*)l, 16, 0, 0);
}

// ===== Packed operand format ("MFMA-native") =====
// Matrix [R rows][K halves] (k-contiguous) -> panels of 16 rows. Per panel,
// per 32-half K-block kb, 64 chunks of 16B in order chunk = k16*16 + row16
// (k16 = which 8-half group, row16 = row within panel). One (panel,kb) block
// = 1KB contiguous. chunk_index(row_g,k) = ((row_g>>4)*(K/32) + (k>>5))*64
//                                          + ((k>>3)&3)*16 + (row_g&15)

// ---------------- pack X: fp32 row-major -> fp16 packed ----------------
__global__ void pack_x_kernel(const float* __restrict__ x, _Float16* __restrict__ xp) {
  __shared__ _Float16 lds[16 * 1032];  // padded stride breaks phase-2 bank aliasing
  int p = blockIdx.x;  // 512 panels of 16 rows x 1024
  const float* src = x + (size_t)p * 16 * 1024;
  for (int it = 0; it < 16; ++it) {
    int idx = it * 256 + threadIdx.x;  // 4096 float4
    int row = idx >> 8, c4 = idx & 255;
    float4 v = ((const float4*)src)[row * 256 + c4];
    half4 h;
    h[0] = (_Float16)v.x; h[1] = (_Float16)v.y; h[2] = (_Float16)v.z; h[3] = (_Float16)v.w;
    *(half4*)(lds + row * 1032 + c4 * 4) = h;
  }
  __syncthreads();
  _Float16* dst = xp + (size_t)p * 2048 * 8;  // 2048 chunks/panel
  for (int it = 0; it < 8; ++it) {
    int c = it * 256 + threadIdx.x;
    int kb = c >> 6, k16 = (c >> 4) & 3, r = c & 15;
    half8 h = *(const half8*)(lds + r * 1032 + kb * 32 + k16 * 8);
    *(half8*)(dst + (size_t)c * 8) = h;  // fully contiguous block write
  }
}

// ---------------- W[k][n] fp32 -> packed Wt[n][k] fp16 (Q|K|V stacked) -------
__global__ void wt_pack_kernel(const float* __restrict__ Wq, const float* __restrict__ Wk,
                               const float* __restrict__ Wv, _Float16* __restrict__ Wtp) {
  __shared__ float tile[32][33];
  int n0 = blockIdx.x * 32, k0 = blockIdx.y * 32, w = blockIdx.z;
  const float* src = (w == 0) ? Wq : (w == 1) ? Wk : Wv;
  int c = threadIdx.x & 31, r8 = threadIdx.x >> 5;
  for (int p = 0; p < 4; ++p) {
    int r = p * 8 + r8;
    tile[r][c] = src[(size_t)(k0 + r) * 1024 + n0 + c];
  }
  __syncthreads();
  if (threadIdx.x < 128) {
    int rr = threadIdx.x & 31;          // n within tile
    int k16 = (threadIdx.x >> 5) & 3;   // 8-half group within k0 block
    half8 h;
    for (int kk = 0; kk < 8; ++kk) h[kk] = (_Float16)tile[k16 * 8 + kk][rr];
    int n_row = w * 1024 + n0 + rr;
    size_t chunk = ((size_t)(n_row >> 4) * 32 + (k0 >> 5)) * 64 + (k16 << 4) + (n_row & 15);
    *(half8*)(Wtp + chunk * 8) = h;
  }
}

// ---------------- V[t][d] row-major fp16 -> packed Vt[d][t] ----------------
__global__ void vt_pack_kernel(const _Float16* __restrict__ V, _Float16* __restrict__ Vtp) {
  __shared__ _Float16 tile[32][33];
  int t0 = blockIdx.x * 32, d0 = blockIdx.y * 32, b = blockIdx.z;
  const _Float16* Vb = V + (size_t)b * 2048 * 1024;
  _Float16* dst = Vtp + (size_t)b * 1024 * 2048;
  int c = threadIdx.x & 31, r8 = threadIdx.x >> 5;
  for (int p = 0; p < 4; ++p) {
    int r = p * 8 + r8;
    tile[r][c] = Vb[(size_t)(t0 + r) * 1024 + d0 + c];  // tile[t-local][d-local]
  }
  __syncthreads();
  if (threadIdx.x < 128) {
    int rr = threadIdx.x & 31;         // d within tile (packed row dim)
    int k16 = (threadIdx.x >> 5) & 3;  // t 8-group within t0 (packed k dim)
    half8 h;
    for (int kk = 0; kk < 8; ++kk) h[kk] = tile[k16 * 8 + kk][rr];
    int d_row = d0 + rr;
    size_t chunk = ((size_t)(d_row >> 4) * 64 + (t0 >> 5)) * 64 + (k16 << 4) + (d_row & 15);
    *(half8*)(dst + chunk * 8) = h;
  }
}

// ---------------- shared GEMM core on packed operands ----------------
// C[128x128] += A~[128 x 32*kIters] * B~[128 x 32*kIters]^T, both packed.
// kbA/kbB = K/32 of the full packed matrix; tA0/tB0 = starting 16-row tile.
// DMA: lane i reads chunk i of a (tile,kb) 1KB block -> fully contiguous.
// LDS: tile-slot-linear; fragment read = slot base + lane*16B (conflict-free).
__device__ __forceinline__ void gemm_core(const _Float16* __restrict__ Ap, int kbA, int tA0,
                                          const _Float16* __restrict__ Bp, int kbB, int tB0,
                                          int kIters, _Float16* sA, _Float16* sB,
                                          floatx4 acc[4][4]) {
  int tid = threadIdx.x;
  int lane = tid & 63, wave = tid >> 6;
  int wm = (wave >> 1) << 6, wn = (wave & 1) << 6;
  // wave stages tiles {2w, 2w+1} of each operand
  const _Float16* gA0 = Ap + ((size_t)(tA0 + 2 * wave) * kbA) * 512 + lane * 8;
  const _Float16* gA1 = Ap + ((size_t)(tA0 + 2 * wave + 1) * kbA) * 512 + lane * 8;
  const _Float16* gB0 = Bp + ((size_t)(tB0 + 2 * wave) * kbB) * 512 + lane * 8;
  const _Float16* gB1 = Bp + ((size_t)(tB0 + 2 * wave + 1) * kbB) * 512 + lane * 8;
  _Float16* lA0 = sA + wave * 1024;  // slots 2w, 2w+1
  _Float16* lA1 = lA0 + 512;
  _Float16* lB0 = sB + wave * 1024;
  _Float16* lB1 = lB0 + 512;
  int ta = wm >> 4, tb = wn >> 4, lo = lane * 8;

  for (int kt = 0; kt < kIters; ++kt) {
    size_t kb = (size_t)kt * 512;  // next 1KB block within each tile
    __syncthreads();
    load_lds16(gA0 + kb, lA0);
    load_lds16(gA1 + kb, lA1);
    load_lds16(gB0 + kb, lB0);
    load_lds16(gB1 + kb, lB1);
    __syncthreads();
    half8 af[4], bf[4];
    for (int i = 0; i < 4; ++i) af[i] = *(const half8*)(sA + (ta + i) * 512 + lo);
    for (int j = 0; j < 4; ++j) bf[j] = *(const half8*)(sB + (tb + j) * 512 + lo);
    for (int i = 0; i < 4; ++i)
      for (int j = 0; j < 4; ++j)
        acc[i][j] = __builtin_amdgcn_mfma_f32_16x16x32_f16(af[i], bf[j], acc[i][j], 0, 0, 0);
  }
}

// ---------------- QKV projection -> Qp/Kp packed, V row-major ----------------
__global__ void qkv_kernel(const _Float16* __restrict__ Xp, const _Float16* __restrict__ Wtp,
                           _Float16* __restrict__ Qp, _Float16* __restrict__ Kp,
                           _Float16* __restrict__ V) {
  __shared__ __align__(16) _Float16 sA[4096];
  __shared__ __align__(16) _Float16 sB[4096];
  floatx4 acc[4][4];
  for (int i = 0; i < 4; ++i)
    for (int j = 0; j < 4; ++j) acc[i][j] = (floatx4){0.f, 0.f, 0.f, 0.f};
  int m0 = blockIdx.y * 128, n0 = blockIdx.x * 128;
  gemm_core(Xp, 32, m0 >> 4, Wtp, 32, n0 >> 4, 32, sA, sB, acc);
  int lane = threadIdx.x & 63, wave = threadIdx.x >> 6;
  int wm = (wave >> 1) << 6, wn = (wave & 1) << 6;
  int quad = lane >> 4, cl = lane & 15;
  int which = n0 >> 10;  // 0=Q 1=K 2=V
  int colbase = (n0 & 1023) + wn;
  for (int i = 0; i < 4; ++i)
    for (int j = 0; j < 4; ++j)
      for (int rr = 0; rr < 4; ++rr) {
        int row_g = m0 + wm + i * 16 + quad * 4 + rr;  // 0..8191
        int col = colbase + j * 16 + cl;               // d
        _Float16 val = (_Float16)acc[i][j][rr];
        if (which == 2) {
          V[(size_t)row_g * 1024 + col] = val;
        } else {
          _Float16* dst = (which == 0) ? Qp : Kp;
          int b = row_g >> 11, t = row_g & 2047;
          size_t chunk = ((size_t)(t >> 4) * 32 + (col >> 5)) * 64 + (((col >> 3) & 3) << 4) + (t & 15);
          dst[(size_t)b * 2097152 + chunk * 8 + (col & 7)] = val;
        }
      }
}

// ---------------- scores: S row-major = Qp.Kp^T / 32, lower tiles only -------
__global__ void qk_kernel(const _Float16* __restrict__ Qp, const _Float16* __restrict__ Kp,
                          _Float16* __restrict__ S) {
  __shared__ __align__(16) _Float16 sA[4096];
  __shared__ __align__(16) _Float16 sB[4096];
  int p = blockIdx.x, b = blockIdx.y;
  int ti = 0;
  while ((ti + 1) * (ti + 2) / 2 <= p) ++ti;
  int tj = p - ti * (ti + 1) / 2;
  const _Float16* Qb = Qp + (size_t)b * 2097152;
  const _Float16* Kb = Kp + (size_t)b * 2097152;
  _Float16* Sb = S + (size_t)b * 4194304;
  floatx4 acc[4][4];
  for (int i = 0; i < 4; ++i)
    for (int j = 0; j < 4; ++j) acc[i][j] = (floatx4){0.f, 0.f, 0.f, 0.f};
  gemm_core(Qb, 32, ti * 8, Kb, 32, tj * 8, 32, sA, sB, acc);
  int lane = threadIdx.x & 63, wave = threadIdx.x >> 6;
  int wm = (wave >> 1) << 6, wn = (wave & 1) << 6;
  int quad = lane >> 4, cl = lane & 15;
  for (int i = 0; i < 4; ++i)
    for (int j = 0; j < 4; ++j)
      for (int rr = 0; rr < 4; ++rr) {
        int row = ti * 128 + wm + i * 16 + quad * 4 + rr;
        int col = tj * 128 + wn + j * 16 + cl;
        float val = acc[i][j][rr] * 0.03125f;  // 1/sqrt(1024)
        if (col > row) val = -INFINITY;        // causal mask (diagonal tiles)
        Sb[(size_t)row * 2048 + col] = (_Float16)val;
      }
}

// ---------------- row softmax: S row-major -> Pp packed ----------------
__global__ void softmax_kernel(const _Float16* __restrict__ S, _Float16* __restrict__ Pp) {
  __shared__ float srow[2048];
  __shared__ float redm[4];
  __shared__ float reds[4];
  int idx = blockIdx.x;
  int b = idx >> 11, t = idx & 2047;
  const _Float16* row = S + ((size_t)b * 2048 + t) * 2048;
  int rowlen = ((t >> 7) + 1) << 7;  // tile-aligned valid length
  int nch = rowlen >> 3;
  int tid = threadIdx.x;
  int lane = tid & 63, wv = tid >> 6;
  float mx = -INFINITY;
  for (int c = tid; c < nch; c += 256) {
    half8 h = *(const half8*)(row + c * 8);
    for (int e = 0; e < 8; ++e) {
      float f = (float)h[e];
      srow[c * 8 + e] = f;
      mx = fmaxf(mx, f);
    }
  }
  for (int o = 32; o; o >>= 1) mx = fmaxf(mx, __shfl_down(mx, o, 64));
  if (lane == 0) redm[wv] = mx;
  __syncthreads();
  mx = fmaxf(fmaxf(redm[0], redm[1]), fmaxf(redm[2], redm[3]));
  float sum = 0.f;
  for (int c = tid; c < nch; c += 256) {
    for (int e = 0; e < 8; ++e) {
      float ev = __expf(srow[c * 8 + e] - mx);  // exp(-inf)=0 handles mask
      srow[c * 8 + e] = ev;
      sum += ev;
    }
  }
  for (int o = 32; o; o >>= 1) sum += __shfl_down(sum, o, 64);
  if (lane == 0) reds[wv] = sum;
  __syncthreads();
  sum = reds[0] + reds[1] + reds[2] + reds[3];
  float inv = 1.0f / sum;
  // write packed: chunk = (t/16, s/32) block, (s/8)%4 group, t%16 row
  _Float16* dst = Pp + (size_t)b * 4194304;
  size_t base = ((size_t)(t >> 4) * 64) * 64 + (t & 15);
  for (int c = tid; c < nch; c += 256) {
    half8 h;
    for (int e = 0; e < 8; ++e) h[e] = (_Float16)(srow[c * 8 + e] * inv);
    size_t chunk = base + (size_t)(c >> 2) * 64 + ((c & 3) << 4);
    *(half8*)(dst + chunk * 8) = h;
  }
}

// ---------------- O = Pp.Vtp^T, fp32 row-major out ----------------
// blockIdx.y remapped so pairs (ti, 15-ti) balance the causal K-loop lengths.
__global__ void pv_kernel(const _Float16* __restrict__ Pp, const _Float16* __restrict__ Vtp,
                          float* __restrict__ out) {
  __shared__ __align__(16) _Float16 sA[4096];
  __shared__ __align__(16) _Float16 sB[4096];
  int n0 = blockIdx.x * 128, b = blockIdx.z;
  int y = blockIdx.y;
  int ti = (y & 1) ? (15 - (y >> 1)) : (y >> 1);
  const _Float16* Pb = Pp + (size_t)b * 4194304;
  const _Float16* Vb = Vtp + (size_t)b * 2097152;
  floatx4 acc[4][4];
  for (int i = 0; i < 4; ++i)
    for (int j = 0; j < 4; ++j) acc[i][j] = (floatx4){0.f, 0.f, 0.f, 0.f};
  gemm_core(Pb, 64, ti * 8, Vb, 64, n0 >> 4, (ti + 1) * 4, sA, sB, acc);  // causal k-limit
  int lane = threadIdx.x & 63, wave = threadIdx.x >> 6;
  int wm = (wave >> 1) << 6, wn = (wave & 1) << 6;
  int quad = lane >> 4, cl = lane & 15;
  for (int i = 0; i < 4; ++i)
    for (int j = 0; j < 4; ++j)
      for (int rr = 0; rr < 4; ++rr) {
        int row = ti * 128 + wm + i * 16 + quad * 4 + rr;  // t
        int col = n0 + wn + j * 16 + cl;                   // d
        float v = acc[i][j][rr];
        out[((size_t)b * 2048 + row) * 1024 + col] = rintf(v * 10000.f) * 1e-4f;
      }
}

extern "C" void kernel_launch(void* const* d_in, const int* in_sizes, int n_in,
                              void* d_out, int out_size, void* d_ws, size_t ws_size,
                              hipStream_t stream) {
  const float* emb = (const float*)d_in[0];
  const float* Wk = (const float*)d_in[1];
  const float* Wq = (const float*)d_in[2];
  const float* Wv = (const float*)d_in[3];
  float* out = (float*)d_out;

  _Float16* ws = (_Float16*)d_ws;
  _Float16* Xp  = ws;                          //  8M halves (packed X)
  _Float16* Wtp = Xp + (size_t)8192 * 1024;    //  3M (packed W^T, Q|K|V)
  _Float16* Qp  = Wtp + (size_t)3072 * 1024;   //  8M (packed)
  _Float16* Kp  = Qp + (size_t)8192 * 1024;    //  8M (packed)
  _Float16* V   = Kp + (size_t)8192 * 1024;    //  8M (row-major)
  _Float16* Vtp = V + (size_t)8192 * 1024;     //  8M (packed)
  _Float16* S   = Vtp + (size_t)8192 * 1024;   // 16M (row-major scores)
  // Pp (16M, packed P) overlaps Xp+Wtp+Qp (19M): all dead before softmax runs.
  _Float16* Pp  = ws;

  pack_x_kernel<<<512, 256, 0, stream>>>(emb, Xp);
  wt_pack_kernel<<<dim3(32, 32, 3), 256, 0, stream>>>(Wq, Wk, Wv, Wtp);
  qkv_kernel<<<dim3(24, 64), 256, 0, stream>>>(Xp, Wtp, Qp, Kp, V);
  vt_pack_kernel<<<dim3(64, 32, 4), 256, 0, stream>>>(V, Vtp);
  qk_kernel<<<dim3(136, 4), 256, 0, stream>>>(Qp, Kp, S);
  softmax_kernel<<<8192, 256, 0, stream>>>(S, Pp);
  pv_kernel<<<dim3(8, 16, 4), 256, 0, stream>>>(Pp, Vtp, out);
}

// Round 5
// 255.964 us; speedup vs baseline: 1.2478x; 1.0159x over previous
//
#include <hip/hip_runtime.h>
#include <cmath>

typedef _Float16 half8 __attribute__((ext_vector_type(8)));
typedef _Float16 half4 __attribute__((ext_vector_type(4)));
typedef float floatx4 __attribute__((ext_vector_type(4)));

// Direct global->LDS DMA, 16B per lane. Per-lane global src; LDS dest =
// wave-uniform base + lane*16.
__device__ __forceinline__ void load_lds16(const void* g, void* l) {
  __builtin_amdgcn_global_load_lds((const __attribute__((address_space(1))) void*)g,
                                   (__attribute__((address_space(3))) void*)l, 16, 0, 0);
}

// ===== Packed operand format ("MFMA-native") =====
// Matrix [R rows][K halves] (k-contiguous) -> panels of 16 rows. Per panel,
// per 32-half K-block kb, 64 chunks of 16B in order chunk = k16*16 + row16.
// One (panel,kb) block = 1KB contiguous.
// chunk_index(row_g,k) = ((row_g>>4)*(K/32) + (k>>5))*64 + ((k>>3)&3)*16 + (row_g&15)

// ---------------- pack X: fp32 row-major -> fp16 packed ----------------
__global__ void pack_x_kernel(const float* __restrict__ x, _Float16* __restrict__ xp) {
  __shared__ _Float16 lds[16 * 1032];  // padded stride breaks phase-2 bank aliasing
  int p = blockIdx.x;  // 512 panels of 16 rows x 1024
  const float* src = x + (size_t)p * 16 * 1024;
  for (int it = 0; it < 16; ++it) {
    int idx = it * 256 + threadIdx.x;  // 4096 float4
    int row = idx >> 8, c4 = idx & 255;
    float4 v = ((const float4*)src)[row * 256 + c4];
    half4 h;
    h[0] = (_Float16)v.x; h[1] = (_Float16)v.y; h[2] = (_Float16)v.z; h[3] = (_Float16)v.w;
    *(half4*)(lds + row * 1032 + c4 * 4) = h;
  }
  __syncthreads();
  _Float16* dst = xp + (size_t)p * 2048 * 8;  // 2048 chunks/panel
  for (int it = 0; it < 8; ++it) {
    int c = it * 256 + threadIdx.x;
    int kb = c >> 6, k16 = (c >> 4) & 3, r = c & 15;
    half8 h = *(const half8*)(lds + r * 1032 + kb * 32 + k16 * 8);
    *(half8*)(dst + (size_t)c * 8) = h;  // fully contiguous block write
  }
}

// ---------------- W[k][n] fp32 -> packed Wt[n][k] fp16 (Q|K|V stacked) -------
__global__ void wt_pack_kernel(const float* __restrict__ Wq, const float* __restrict__ Wk,
                               const float* __restrict__ Wv, _Float16* __restrict__ Wtp) {
  __shared__ float tile[32][33];
  int n0 = blockIdx.x * 32, k0 = blockIdx.y * 32, w = blockIdx.z;
  const float* src = (w == 0) ? Wq : (w == 1) ? Wk : Wv;
  int c = threadIdx.x & 31, r8 = threadIdx.x >> 5;
  for (int p = 0; p < 4; ++p) {
    int r = p * 8 + r8;
    tile[r][c] = src[(size_t)(k0 + r) * 1024 + n0 + c];
  }
  __syncthreads();
  if (threadIdx.x < 128) {
    int rr = threadIdx.x & 31;          // n within tile
    int k16 = (threadIdx.x >> 5) & 3;   // 8-half group within k0 block
    half8 h;
    for (int kk = 0; kk < 8; ++kk) h[kk] = (_Float16)tile[k16 * 8 + kk][rr];
    int n_row = w * 1024 + n0 + rr;
    size_t chunk = ((size_t)(n_row >> 4) * 32 + (k0 >> 5)) * 64 + (k16 << 4) + (n_row & 15);
    *(half8*)(Wtp + chunk * 8) = h;
  }
}

// ---------------- V[t][d] row-major fp16 -> packed Vt[d][t] ----------------
__global__ void vt_pack_kernel(const _Float16* __restrict__ V, _Float16* __restrict__ Vtp) {
  __shared__ _Float16 tile[32][33];
  int t0 = blockIdx.x * 32, d0 = blockIdx.y * 32, b = blockIdx.z;
  const _Float16* Vb = V + (size_t)b * 2048 * 1024;
  _Float16* dst = Vtp + (size_t)b * 1024 * 2048;
  int c = threadIdx.x & 31, r8 = threadIdx.x >> 5;
  for (int p = 0; p < 4; ++p) {
    int r = p * 8 + r8;
    tile[r][c] = Vb[(size_t)(t0 + r) * 1024 + d0 + c];  // tile[t-local][d-local]
  }
  __syncthreads();
  if (threadIdx.x < 128) {
    int rr = threadIdx.x & 31;         // d within tile (packed row dim)
    int k16 = (threadIdx.x >> 5) & 3;  // t 8-group within t0 (packed k dim)
    half8 h;
    for (int kk = 0; kk < 8; ++kk) h[kk] = tile[k16 * 8 + kk][rr];
    int d_row = d0 + rr;
    size_t chunk = ((size_t)(d_row >> 4) * 64 + (t0 >> 5)) * 64 + (k16 << 4) + (d_row & 15);
    *(half8*)(dst + chunk * 8) = h;
  }
}

// ---------------- shared GEMM core on packed operands ----------------
// C[128x128] += A~ * B~^T, both packed. kbA/kbB = K/32; tA0/tB0 = start tile.
// DMA: lane i reads chunk i of a (tile,kb) 1KB block -> fully contiguous.
// LDS: tile-slot-linear; fragment read = slot base + lane*16B (conflict-free).
__device__ __forceinline__ void gemm_core(const _Float16* __restrict__ Ap, int kbA, int tA0,
                                          const _Float16* __restrict__ Bp, int kbB, int tB0,
                                          int kIters, _Float16* sA, _Float16* sB,
                                          floatx4 acc[4][4]) {
  int tid = threadIdx.x;
  int lane = tid & 63, wave = tid >> 6;
  int wm = (wave >> 1) << 6, wn = (wave & 1) << 6;
  // wave stages tiles {2w, 2w+1} of each operand
  const _Float16* gA0 = Ap + ((size_t)(tA0 + 2 * wave) * kbA) * 512 + lane * 8;
  const _Float16* gA1 = Ap + ((size_t)(tA0 + 2 * wave + 1) * kbA) * 512 + lane * 8;
  const _Float16* gB0 = Bp + ((size_t)(tB0 + 2 * wave) * kbB) * 512 + lane * 8;
  const _Float16* gB1 = Bp + ((size_t)(tB0 + 2 * wave + 1) * kbB) * 512 + lane * 8;
  _Float16* lA0 = sA + wave * 1024;  // slots 2w, 2w+1
  _Float16* lA1 = lA0 + 512;
  _Float16* lB0 = sB + wave * 1024;
  _Float16* lB1 = lB0 + 512;
  int ta = wm >> 4, tb = wn >> 4, lo = lane * 8;

  for (int kt = 0; kt < kIters; ++kt) {
    size_t kb = (size_t)kt * 512;  // next 1KB block within each tile
    __syncthreads();
    load_lds16(gA0 + kb, lA0);
    load_lds16(gA1 + kb, lA1);
    load_lds16(gB0 + kb, lB0);
    load_lds16(gB1 + kb, lB1);
    __syncthreads();
    half8 af[4], bf[4];
    for (int i = 0; i < 4; ++i) af[i] = *(const half8*)(sA + (ta + i) * 512 + lo);
    for (int j = 0; j < 4; ++j) bf[j] = *(const half8*)(sB + (tb + j) * 512 + lo);
    for (int i = 0; i < 4; ++i)
      for (int j = 0; j < 4; ++j)
        acc[i][j] = __builtin_amdgcn_mfma_f32_16x16x32_f16(af[i], bf[j], acc[i][j], 0, 0, 0);
  }
}

// ---------------- QKV projection -> Qp/Kp packed, V row-major ----------------
__global__ void qkv_kernel(const _Float16* __restrict__ Xp, const _Float16* __restrict__ Wtp,
                           _Float16* __restrict__ Qp, _Float16* __restrict__ Kp,
                           _Float16* __restrict__ V) {
  __shared__ __align__(16) _Float16 sA[4096];
  __shared__ __align__(16) _Float16 sB[4096];
  floatx4 acc[4][4];
  for (int i = 0; i < 4; ++i)
    for (int j = 0; j < 4; ++j) acc[i][j] = (floatx4){0.f, 0.f, 0.f, 0.f};
  int m0 = blockIdx.y * 128, n0 = blockIdx.x * 128;
  gemm_core(Xp, 32, m0 >> 4, Wtp, 32, n0 >> 4, 32, sA, sB, acc);
  int lane = threadIdx.x & 63, wave = threadIdx.x >> 6;
  int wm = (wave >> 1) << 6, wn = (wave & 1) << 6;
  int quad = lane >> 4, cl = lane & 15;
  int which = n0 >> 10;  // 0=Q 1=K 2=V
  int colbase = (n0 & 1023) + wn;
  for (int i = 0; i < 4; ++i)
    for (int j = 0; j < 4; ++j)
      for (int rr = 0; rr < 4; ++rr) {
        int row_g = m0 + wm + i * 16 + quad * 4 + rr;  // 0..8191
        int col = colbase + j * 16 + cl;               // d
        _Float16 val = (_Float16)acc[i][j][rr];
        if (which == 2) {
          V[(size_t)row_g * 1024 + col] = val;
        } else {
          _Float16* dst = (which == 0) ? Qp : Kp;
          int b = row_g >> 11, t = row_g & 2047;
          size_t chunk = ((size_t)(t >> 4) * 32 + (col >> 5)) * 64 + (((col >> 3) & 3) << 4) + (t & 15);
          dst[(size_t)b * 2097152 + chunk * 8 + (col & 7)] = val;
        }
      }
}

// ---------------- scores: S PACKED = Qp.Kp^T / 32, lower tiles only ----------
__global__ void qk_kernel(const _Float16* __restrict__ Qp, const _Float16* __restrict__ Kp,
                          _Float16* __restrict__ S) {
  __shared__ __align__(16) _Float16 sA[4096];
  __shared__ __align__(16) _Float16 sB[4096];
  int p = blockIdx.x, b = blockIdx.y;
  int ti = 0;
  while ((ti + 1) * (ti + 2) / 2 <= p) ++ti;
  int tj = p - ti * (ti + 1) / 2;
  const _Float16* Qb = Qp + (size_t)b * 2097152;
  const _Float16* Kb = Kp + (size_t)b * 2097152;
  _Float16* Sb = S + (size_t)b * 4194304;
  floatx4 acc[4][4];
  for (int i = 0; i < 4; ++i)
    for (int j = 0; j < 4; ++j) acc[i][j] = (floatx4){0.f, 0.f, 0.f, 0.f};
  gemm_core(Qb, 32, ti * 8, Kb, 32, tj * 8, 32, sA, sB, acc);
  int lane = threadIdx.x & 63, wave = threadIdx.x >> 6;
  int wm = (wave >> 1) << 6, wn = (wave & 1) << 6;
  int quad = lane >> 4, cl = lane & 15;
  for (int i = 0; i < 4; ++i)
    for (int j = 0; j < 4; ++j)
      for (int rr = 0; rr < 4; ++rr) {
        int row = ti * 128 + wm + i * 16 + quad * 4 + rr;  // t
        int col = tj * 128 + wn + j * 16 + cl;             // s
        float val = acc[i][j][rr] * 0.03125f;  // 1/sqrt(1024)
        if (col > row) val = -INFINITY;        // causal mask (diagonal tiles)
        // packed store (quad-contiguous 2B pattern; K=2048 -> 64 kb/panel)
        size_t chunk = ((size_t)(row >> 4) * 64 + (col >> 5)) * 64 + (((col >> 3) & 3) << 4) + (row & 15);
        Sb[chunk * 8 + (col & 7)] = (_Float16)val;
      }
}

// ---------------- softmax over packed S, in place, 16-row panel per block ----
// Panel-uniform valid length (16-row panels never cross a 128 boundary).
// In packed chunk order lane l holds row l&15 -> row stats via shfl_xor(16,32)
// + 4x16 LDS patch across waves. Values kept in regs (<=16 half8 = 64 VGPR).
__global__ void softmax_kernel(_Float16* __restrict__ S) {
  __shared__ float redm[4][16];
  __shared__ float reds[4][16];
  int p = blockIdx.x, b = blockIdx.y;  // panel, batch
  _Float16* panel = S + (size_t)b * 4194304 + (size_t)p * 32768;  // 64 kb * 512 halves
  int nkb = ((p >> 3) + 1) * 4;  // valid 32-col blocks for rows in this panel
  int tid = threadIdx.x, lane = tid & 63, w = tid >> 6;
  int row = lane & 15;

  half8 v[16];
  float mx = -INFINITY;
  for (int it = 0; it < 16; ++it) {
    int kb = w + it * 4;
    if (kb < nkb) {
      v[it] = *(const half8*)(panel + (size_t)kb * 512 + lane * 8);
      for (int e = 0; e < 8; ++e) mx = fmaxf(mx, (float)v[it][e]);
    }
  }
  mx = fmaxf(mx, __shfl_xor(mx, 16, 64));
  mx = fmaxf(mx, __shfl_xor(mx, 32, 64));
  if (lane < 16) redm[w][lane] = mx;
  __syncthreads();
  mx = fmaxf(fmaxf(redm[0][row], redm[1][row]), fmaxf(redm[2][row], redm[3][row]));

  float sum = 0.f;
  for (int it = 0; it < 16; ++it) {
    int kb = w + it * 4;
    if (kb < nkb) {
      for (int e = 0; e < 8; ++e) {
        float ev = __expf((float)v[it][e] - mx);  // exp(-inf)=0 handles mask
        v[it][e] = (_Float16)ev;
        sum += ev;
      }
    }
  }
  sum += __shfl_xor(sum, 16, 64);
  sum += __shfl_xor(sum, 32, 64);
  if (lane < 16) reds[w][lane] = sum;
  __syncthreads();
  sum = reds[0][row] + reds[1][row] + reds[2][row] + reds[3][row];
  float inv = 1.0f / sum;

  for (int it = 0; it < 16; ++it) {
    int kb = w + it * 4;
    if (kb < nkb) {
      half8 h;
      for (int e = 0; e < 8; ++e) h[e] = (_Float16)((float)v[it][e] * inv);
      *(half8*)(panel + (size_t)kb * 512 + lane * 8) = h;
    }
  }
}

// ---------------- O = P.Vtp^T, fp32 row-major out ----------------
// blockIdx.y remapped so pairs (ti, 15-ti) balance the causal K-loop lengths.
__global__ void pv_kernel(const _Float16* __restrict__ P, const _Float16* __restrict__ Vtp,
                          float* __restrict__ out) {
  __shared__ __align__(16) _Float16 sA[4096];
  __shared__ __align__(16) _Float16 sB[4096];
  int n0 = blockIdx.x * 128, b = blockIdx.z;
  int y = blockIdx.y;
  int ti = (y & 1) ? (15 - (y >> 1)) : (y >> 1);
  const _Float16* Pb = P + (size_t)b * 4194304;
  const _Float16* Vb = Vtp + (size_t)b * 2097152;
  floatx4 acc[4][4];
  for (int i = 0; i < 4; ++i)
    for (int j = 0; j < 4; ++j) acc[i][j] = (floatx4){0.f, 0.f, 0.f, 0.f};
  gemm_core(Pb, 64, ti * 8, Vb, 64, n0 >> 4, (ti + 1) * 4, sA, sB, acc);  // causal k-limit
  int lane = threadIdx.x & 63, wave = threadIdx.x >> 6;
  int wm = (wave >> 1) << 6, wn = (wave & 1) << 6;
  int quad = lane >> 4, cl = lane & 15;
  for (int i = 0; i < 4; ++i)
    for (int j = 0; j < 4; ++j)
      for (int rr = 0; rr < 4; ++rr) {
        int row = ti * 128 + wm + i * 16 + quad * 4 + rr;  // t
        int col = n0 + wn + j * 16 + cl;                   // d
        float v = acc[i][j][rr];
        out[((size_t)b * 2048 + row) * 1024 + col] = rintf(v * 10000.f) * 1e-4f;
      }
}

extern "C" void kernel_launch(void* const* d_in, const int* in_sizes, int n_in,
                              void* d_out, int out_size, void* d_ws, size_t ws_size,
                              hipStream_t stream) {
  const float* emb = (const float*)d_in[0];
  const float* Wk = (const float*)d_in[1];
  const float* Wq = (const float*)d_in[2];
  const float* Wv = (const float*)d_in[3];
  float* out = (float*)d_out;

  _Float16* ws = (_Float16*)d_ws;
  _Float16* Xp  = ws;                          //  8M halves (packed X)
  _Float16* Wtp = Xp + (size_t)8192 * 1024;    //  3M (packed W^T, Q|K|V)
  _Float16* Qp  = Wtp + (size_t)3072 * 1024;   //  8M (packed)
  _Float16* Kp  = Qp + (size_t)8192 * 1024;    //  8M (packed)
  _Float16* V   = Kp + (size_t)8192 * 1024;    //  8M (row-major)
  _Float16* Vtp = V + (size_t)8192 * 1024;     //  8M (packed)
  _Float16* S   = Vtp + (size_t)8192 * 1024;   // 16M (packed scores; becomes P in place)

  pack_x_kernel<<<512, 256, 0, stream>>>(emb, Xp);
  wt_pack_kernel<<<dim3(32, 32, 3), 256, 0, stream>>>(Wq, Wk, Wv, Wtp);
  qkv_kernel<<<dim3(24, 64), 256, 0, stream>>>(Xp, Wtp, Qp, Kp, V);
  vt_pack_kernel<<<dim3(64, 32, 4), 256, 0, stream>>>(V, Vtp);
  qk_kernel<<<dim3(136, 4), 256, 0, stream>>>(Qp, Kp, S);
  softmax_kernel<<<dim3(128, 4), 256, 0, stream>>>(S);
  pv_kernel<<<dim3(8, 16, 4), 256, 0, stream>>>(S, Vtp, out);
}

// Round 6
// 250.993 us; speedup vs baseline: 1.2725x; 1.0198x over previous
//
#include <hip/hip_runtime.h>
#include <cmath>

typedef _Float16 half8 __attribute__((ext_vector_type(8)));
typedef _Float16 half4 __attribute__((ext_vector_type(4)));
typedef float floatx4 __attribute__((ext_vector_type(4)));

// Direct global->LDS DMA, 16B per lane. Per-lane global src; LDS dest =
// wave-uniform base + lane*16.
__device__ __forceinline__ void load_lds16(const void* g, void* l) {
  __builtin_amdgcn_global_load_lds((const __attribute__((address_space(1))) void*)g,
                                   (__attribute__((address_space(3))) void*)l, 16, 0, 0);
}

// ===== Packed operand format ("MFMA-native") =====
// Matrix [R rows][K halves] (k-contiguous) -> panels of 16 rows. Per panel,
// per 32-half K-block kb, 64 chunks of 16B in order chunk = k16*16 + row16.
// One (panel,kb) block = 1KB contiguous; kb blocks contiguous within a panel.
// chunk_index(row_g,k) = ((row_g>>4)*(K/32) + (k>>5))*64 + ((k>>3)&3)*16 + (row_g&15)

// ---------------- pack X: fp32 row-major -> fp16 packed ----------------
__global__ void pack_x_kernel(const float* __restrict__ x, _Float16* __restrict__ xp) {
  __shared__ _Float16 lds[16 * 1032];  // padded stride breaks phase-2 bank aliasing
  int p = blockIdx.x;  // 512 panels of 16 rows x 1024
  const float* src = x + (size_t)p * 16 * 1024;
  for (int it = 0; it < 16; ++it) {
    int idx = it * 256 + threadIdx.x;  // 4096 float4
    int row = idx >> 8, c4 = idx & 255;
    float4 v = ((const float4*)src)[row * 256 + c4];
    half4 h;
    h[0] = (_Float16)v.x; h[1] = (_Float16)v.y; h[2] = (_Float16)v.z; h[3] = (_Float16)v.w;
    *(half4*)(lds + row * 1032 + c4 * 4) = h;
  }
  __syncthreads();
  _Float16* dst = xp + (size_t)p * 2048 * 8;  // 2048 chunks/panel
  for (int it = 0; it < 8; ++it) {
    int c = it * 256 + threadIdx.x;
    int kb = c >> 6, k16 = (c >> 4) & 3, r = c & 15;
    half8 h = *(const half8*)(lds + r * 1032 + kb * 32 + k16 * 8);
    *(half8*)(dst + (size_t)c * 8) = h;  // fully contiguous block write
  }
}

// ---------------- W[k][n] fp32 -> packed Wt[n][k] fp16 (Q|K|V stacked) -------
__global__ void wt_pack_kernel(const float* __restrict__ Wq, const float* __restrict__ Wk,
                               const float* __restrict__ Wv, _Float16* __restrict__ Wtp) {
  __shared__ float tile[32][33];
  int n0 = blockIdx.x * 32, k0 = blockIdx.y * 32, w = blockIdx.z;
  const float* src = (w == 0) ? Wq : (w == 1) ? Wk : Wv;
  int c = threadIdx.x & 31, r8 = threadIdx.x >> 5;
  for (int p = 0; p < 4; ++p) {
    int r = p * 8 + r8;
    tile[r][c] = src[(size_t)(k0 + r) * 1024 + n0 + c];
  }
  __syncthreads();
  if (threadIdx.x < 128) {
    int rr = threadIdx.x & 31;          // n within tile
    int k16 = (threadIdx.x >> 5) & 3;   // 8-half group within k0 block
    half8 h;
    for (int kk = 0; kk < 8; ++kk) h[kk] = (_Float16)tile[k16 * 8 + kk][rr];
    int n_row = w * 1024 + n0 + rr;
    size_t chunk = ((size_t)(n_row >> 4) * 32 + (k0 >> 5)) * 64 + (k16 << 4) + (n_row & 15);
    *(half8*)(Wtp + chunk * 8) = h;
  }
}

// ---------------- shared GEMM core, BK=64 (2 kb-blocks per barrier) ----------
// C[128x128] += A~ * B~^T, both packed. kbA/kbB = K/32 of the packed matrix;
// tA0/tB0 = starting 16-row tile; kPeriods = K-extent/64.
// Per period each wave stages tiles {2w,2w+1} x 2 consecutive 1KB kb-blocks
// (4 DMAs/operand). LDS slot s = tile*2 + u (u = kb phase), 512 halves/slot.
// DMA writes and fragment reads are both lane-linear 1KB -> conflict-free.
__device__ __forceinline__ void gemm_core(const _Float16* __restrict__ Ap, int kbA, int tA0,
                                          const _Float16* __restrict__ Bp, int kbB, int tB0,
                                          int kPeriods, _Float16* sA, _Float16* sB,
                                          floatx4 acc[4][4]) {
  int tid = threadIdx.x;
  int lane = tid & 63, wave = tid >> 6;
  int wm = (wave >> 1) << 6, wn = (wave & 1) << 6;
  const _Float16* gA0 = Ap + ((size_t)(tA0 + 2 * wave) * kbA) * 512 + lane * 8;
  const _Float16* gA1 = Ap + ((size_t)(tA0 + 2 * wave + 1) * kbA) * 512 + lane * 8;
  const _Float16* gB0 = Bp + ((size_t)(tB0 + 2 * wave) * kbB) * 512 + lane * 8;
  const _Float16* gB1 = Bp + ((size_t)(tB0 + 2 * wave + 1) * kbB) * 512 + lane * 8;
  _Float16* lA = sA + wave * 2048;  // slots 4w..4w+3
  _Float16* lB = sB + wave * 2048;
  int ta = wm >> 4, tb = wn >> 4, lo = lane * 8;

  for (int kt = 0; kt < kPeriods; ++kt) {
    size_t kb = (size_t)kt * 1024;  // 2 consecutive 1KB blocks per tile
    __syncthreads();
    load_lds16(gA0 + kb, lA);
    load_lds16(gA0 + kb + 512, lA + 512);
    load_lds16(gA1 + kb, lA + 1024);
    load_lds16(gA1 + kb + 512, lA + 1536);
    load_lds16(gB0 + kb, lB);
    load_lds16(gB0 + kb + 512, lB + 512);
    load_lds16(gB1 + kb, lB + 1024);
    load_lds16(gB1 + kb + 512, lB + 1536);
    __syncthreads();
    for (int u = 0; u < 2; ++u) {
      half8 af[4], bf[4];
      for (int i = 0; i < 4; ++i) af[i] = *(const half8*)(sA + (((ta + i) << 1) + u) * 512 + lo);
      for (int j = 0; j < 4; ++j) bf[j] = *(const half8*)(sB + (((tb + j) << 1) + u) * 512 + lo);
      for (int i = 0; i < 4; ++i)
        for (int j = 0; j < 4; ++j)
          acc[i][j] = __builtin_amdgcn_mfma_f32_16x16x32_f16(af[i], bf[j], acc[i][j], 0, 0, 0);
    }
  }
}

// ---------------- QKV projection -> Qp/Kp packed, V directly packed as Vtp ---
__global__ void qkv_kernel(const _Float16* __restrict__ Xp, const _Float16* __restrict__ Wtp,
                           _Float16* __restrict__ Qp, _Float16* __restrict__ Kp,
                           _Float16* __restrict__ Vtp) {
  __shared__ __align__(16) _Float16 sA[8192];
  __shared__ __align__(16) _Float16 sB[8192];
  floatx4 acc[4][4];
  for (int i = 0; i < 4; ++i)
    for (int j = 0; j < 4; ++j) acc[i][j] = (floatx4){0.f, 0.f, 0.f, 0.f};
  int m0 = blockIdx.y * 128, n0 = blockIdx.x * 128;
  gemm_core(Xp, 32, m0 >> 4, Wtp, 32, n0 >> 4, 16, sA, sB, acc);
  int lane = threadIdx.x & 63, wave = threadIdx.x >> 6;
  int wm = (wave >> 1) << 6, wn = (wave & 1) << 6;
  int quad = lane >> 4, cl = lane & 15;
  int which = n0 >> 10;  // 0=Q 1=K 2=V
  int colbase = (n0 & 1023) + wn;
  for (int i = 0; i < 4; ++i)
    for (int j = 0; j < 4; ++j)
      for (int rr = 0; rr < 4; ++rr) {
        int row_g = m0 + wm + i * 16 + quad * 4 + rr;  // 0..8191
        int col = colbase + j * 16 + cl;               // d
        _Float16 val = (_Float16)acc[i][j][rr];
        int b = row_g >> 11, t = row_g & 2047;
        if (which == 2) {
          // packed Vt[d][t]: row dim = d (col), k dim = t
          size_t chunk = ((size_t)(col >> 4) * 64 + (t >> 5)) * 64 + (((t >> 3) & 3) << 4) + (col & 15);
          Vtp[(size_t)b * 2097152 + chunk * 8 + (t & 7)] = val;
        } else {
          _Float16* dst = (which == 0) ? Qp : Kp;
          size_t chunk = ((size_t)(t >> 4) * 32 + (col >> 5)) * 64 + (((col >> 3) & 3) << 4) + (t & 15);
          dst[(size_t)b * 2097152 + chunk * 8 + (col & 7)] = val;
        }
      }
}

// ---------------- scores: S PACKED = Qp.Kp^T / 32, lower tiles only ----------
__global__ void qk_kernel(const _Float16* __restrict__ Qp, const _Float16* __restrict__ Kp,
                          _Float16* __restrict__ S) {
  __shared__ __align__(16) _Float16 sA[8192];
  __shared__ __align__(16) _Float16 sB[8192];
  int p = blockIdx.x, b = blockIdx.y;
  int ti = 0;
  while ((ti + 1) * (ti + 2) / 2 <= p) ++ti;
  int tj = p - ti * (ti + 1) / 2;
  const _Float16* Qb = Qp + (size_t)b * 2097152;
  const _Float16* Kb = Kp + (size_t)b * 2097152;
  _Float16* Sb = S + (size_t)b * 4194304;
  floatx4 acc[4][4];
  for (int i = 0; i < 4; ++i)
    for (int j = 0; j < 4; ++j) acc[i][j] = (floatx4){0.f, 0.f, 0.f, 0.f};
  gemm_core(Qb, 32, ti * 8, Kb, 32, tj * 8, 16, sA, sB, acc);
  int lane = threadIdx.x & 63, wave = threadIdx.x >> 6;
  int wm = (wave >> 1) << 6, wn = (wave & 1) << 6;
  int quad = lane >> 4, cl = lane & 15;
  for (int i = 0; i < 4; ++i)
    for (int j = 0; j < 4; ++j)
      for (int rr = 0; rr < 4; ++rr) {
        int row = ti * 128 + wm + i * 16 + quad * 4 + rr;  // t
        int col = tj * 128 + wn + j * 16 + cl;             // s
        float val = acc[i][j][rr] * 0.03125f;  // 1/sqrt(1024)
        if (col > row) val = -INFINITY;        // causal mask (diagonal tiles)
        // packed store (quad-contiguous 2B pattern; K=2048 -> 64 kb/panel)
        size_t chunk = ((size_t)(row >> 4) * 64 + (col >> 5)) * 64 + (((col >> 3) & 3) << 4) + (row & 15);
        Sb[chunk * 8 + (col & 7)] = (_Float16)val;
      }
}

// ---------------- softmax over packed S, in place, 16-row panel per block ----
// Panel-uniform valid length (16-row panels never cross a 128 boundary).
// In packed chunk order lane l holds row l&15 -> row stats via shfl_xor(16,32)
// + 4x16 LDS patch across waves. Values kept in regs (<=16 half8 = 64 VGPR).
__global__ void softmax_kernel(_Float16* __restrict__ S) {
  __shared__ float redm[4][16];
  __shared__ float reds[4][16];
  int p = blockIdx.x, b = blockIdx.y;  // panel, batch
  _Float16* panel = S + (size_t)b * 4194304 + (size_t)p * 32768;  // 64 kb * 512 halves
  int nkb = ((p >> 3) + 1) * 4;  // valid 32-col blocks for rows in this panel
  int tid = threadIdx.x, lane = tid & 63, w = tid >> 6;
  int row = lane & 15;

  half8 v[16];
  float mx = -INFINITY;
  for (int it = 0; it < 16; ++it) {
    int kb = w + it * 4;
    if (kb < nkb) {
      v[it] = *(const half8*)(panel + (size_t)kb * 512 + lane * 8);
      for (int e = 0; e < 8; ++e) mx = fmaxf(mx, (float)v[it][e]);
    }
  }
  mx = fmaxf(mx, __shfl_xor(mx, 16, 64));
  mx = fmaxf(mx, __shfl_xor(mx, 32, 64));
  if (lane < 16) redm[w][lane] = mx;
  __syncthreads();
  mx = fmaxf(fmaxf(redm[0][row], redm[1][row]), fmaxf(redm[2][row], redm[3][row]));

  float sum = 0.f;
  for (int it = 0; it < 16; ++it) {
    int kb = w + it * 4;
    if (kb < nkb) {
      for (int e = 0; e < 8; ++e) {
        float ev = __expf((float)v[it][e] - mx);  // exp(-inf)=0 handles mask
        v[it][e] = (_Float16)ev;
        sum += ev;
      }
    }
  }
  sum += __shfl_xor(sum, 16, 64);
  sum += __shfl_xor(sum, 32, 64);
  if (lane < 16) reds[w][lane] = sum;
  __syncthreads();
  sum = reds[0][row] + reds[1][row] + reds[2][row] + reds[3][row];
  float inv = 1.0f / sum;

  for (int it = 0; it < 16; ++it) {
    int kb = w + it * 4;
    if (kb < nkb) {
      half8 h;
      for (int e = 0; e < 8; ++e) h[e] = (_Float16)((float)v[it][e] * inv);
      *(half8*)(panel + (size_t)kb * 512 + lane * 8) = h;
    }
  }
}

// ---------------- O = P.Vtp^T, fp32 row-major out ----------------
// blockIdx.y remapped so pairs (ti, 15-ti) balance the causal K-loop lengths.
__global__ void pv_kernel(const _Float16* __restrict__ P, const _Float16* __restrict__ Vtp,
                          float* __restrict__ out) {
  __shared__ __align__(16) _Float16 sA[8192];
  __shared__ __align__(16) _Float16 sB[8192];
  int n0 = blockIdx.x * 128, b = blockIdx.z;
  int y = blockIdx.y;
  int ti = (y & 1) ? (15 - (y >> 1)) : (y >> 1);
  const _Float16* Pb = P + (size_t)b * 4194304;
  const _Float16* Vb = Vtp + (size_t)b * 2097152;
  floatx4 acc[4][4];
  for (int i = 0; i < 4; ++i)
    for (int j = 0; j < 4; ++j) acc[i][j] = (floatx4){0.f, 0.f, 0.f, 0.f};
  gemm_core(Pb, 64, ti * 8, Vb, 64, n0 >> 4, (ti + 1) * 2, sA, sB, acc);  // causal k-limit
  int lane = threadIdx.x & 63, wave = threadIdx.x >> 6;
  int wm = (wave >> 1) << 6, wn = (wave & 1) << 6;
  int quad = lane >> 4, cl = lane & 15;
  for (int i = 0; i < 4; ++i)
    for (int j = 0; j < 4; ++j)
      for (int rr = 0; rr < 4; ++rr) {
        int row = ti * 128 + wm + i * 16 + quad * 4 + rr;  // t
        int col = n0 + wn + j * 16 + cl;                   // d
        float v = acc[i][j][rr];
        out[((size_t)b * 2048 + row) * 1024 + col] = rintf(v * 10000.f) * 1e-4f;
      }
}

extern "C" void kernel_launch(void* const* d_in, const int* in_sizes, int n_in,
                              void* d_out, int out_size, void* d_ws, size_t ws_size,
                              hipStream_t stream) {
  const float* emb = (const float*)d_in[0];
  const float* Wk = (const float*)d_in[1];
  const float* Wq = (const float*)d_in[2];
  const float* Wv = (const float*)d_in[3];
  float* out = (float*)d_out;

  _Float16* ws = (_Float16*)d_ws;
  _Float16* Xp  = ws;                          //  8M halves (packed X)
  _Float16* Wtp = Xp + (size_t)8192 * 1024;    //  3M (packed W^T, Q|K|V)
  _Float16* Qp  = Wtp + (size_t)3072 * 1024;   //  8M (packed)
  _Float16* Kp  = Qp + (size_t)8192 * 1024;    //  8M (packed)
  _Float16* Vtp = Kp + (size_t)8192 * 1024;    //  8M (packed Vt[d][t], written by qkv)
  _Float16* S   = Vtp + (size_t)8192 * 1024;   // 16M (packed scores; becomes P in place)

  pack_x_kernel<<<512, 256, 0, stream>>>(emb, Xp);
  wt_pack_kernel<<<dim3(32, 32, 3), 256, 0, stream>>>(Wq, Wk, Wv, Wtp);
  qkv_kernel<<<dim3(24, 64), 256, 0, stream>>>(Xp, Wtp, Qp, Kp, Vtp);
  qk_kernel<<<dim3(136, 4), 256, 0, stream>>>(Qp, Kp, S);
  softmax_kernel<<<dim3(128, 4), 256, 0, stream>>>(S);
  pv_kernel<<<dim3(8, 16, 4), 256, 0, stream>>>(S, Vtp, out);
}

// Round 8
// 250.344 us; speedup vs baseline: 1.2758x; 1.0026x over previous
//
#include <hip/hip_runtime.h>
#include <cmath>

typedef _Float16 half8 __attribute__((ext_vector_type(8)));
typedef _Float16 half4 __attribute__((ext_vector_type(4)));
typedef float floatx4 __attribute__((ext_vector_type(4)));

// Direct global->LDS DMA, 16B per lane. Per-lane global src; LDS dest =
// wave-uniform base + lane*16.
__device__ __forceinline__ void load_lds16(const void* g, void* l) {
  __builtin_amdgcn_global_load_lds((const __attribute__((address_space(1))) void*)g,
                                   (__attribute__((address_space(3))) void*)l, 16, 0, 0);
}

// ===== Packed operand format ("MFMA-native") =====
// Matrix [R rows][K halves] (k-contiguous) -> panels of 16 rows. Per panel,
// per 32-half K-block kb, 64 chunks of 16B in order chunk = k16*16 + row16.
// One (panel,kb) block = 1KB contiguous; kb blocks contiguous within a panel.
// chunk_index(row_g,k) = ((row_g>>4)*(K/32) + (k>>5))*64 + ((k>>3)&3)*16 + (row_g&15)

// ---------------- prep: pack X/Wq/Wk rows + transpose-pack Wv ----------------
// p < 512: X panel p; 512..575: Wq panel; 576..639: Wk panel (identical code,
// fp32 16x1024 -> packed fp16). p >= 640: Wv 32x32 transpose-pack tile.
__global__ void prep_kernel(const float* __restrict__ emb, const float* __restrict__ Wq,
                            const float* __restrict__ Wk, const float* __restrict__ Wv,
                            _Float16* __restrict__ Xp, _Float16* __restrict__ Wqp,
                            _Float16* __restrict__ Wkp, _Float16* __restrict__ Wvtp) {
  int p = blockIdx.x;
  if (p < 640) {
    __shared__ _Float16 lds[16 * 1032];  // padded stride breaks bank aliasing
    const float* src;
    _Float16* dst;
    if (p < 512)      { src = emb + (size_t)p * 16384;        dst = Xp  + (size_t)p * 16384; }
    else if (p < 576) { src = Wq + (size_t)(p - 512) * 16384; dst = Wqp + (size_t)(p - 512) * 16384; }
    else              { src = Wk + (size_t)(p - 576) * 16384; dst = Wkp + (size_t)(p - 576) * 16384; }
    for (int it = 0; it < 16; ++it) {
      int idx = it * 256 + threadIdx.x;  // 4096 float4
      int row = idx >> 8, c4 = idx & 255;
      float4 v = ((const float4*)src)[row * 256 + c4];
      half4 h;
      h[0] = (_Float16)v.x; h[1] = (_Float16)v.y; h[2] = (_Float16)v.z; h[3] = (_Float16)v.w;
      *(half4*)(lds + row * 1032 + c4 * 4) = h;
    }
    __syncthreads();
    for (int it = 0; it < 8; ++it) {
      int c = it * 256 + threadIdx.x;
      int kb = c >> 6, k16 = (c >> 4) & 3, r = c & 15;
      half8 h = *(const half8*)(lds + r * 1032 + kb * 32 + k16 * 8);
      *(half8*)(dst + (size_t)c * 8) = h;  // fully contiguous block write
    }
  } else {
    __shared__ float tile[32][33];
    int q = p - 640;
    int n0 = (q & 31) * 32, k0 = (q >> 5) * 32;
    int c = threadIdx.x & 31, r8 = threadIdx.x >> 5;
    for (int pp = 0; pp < 4; ++pp) {
      int r = pp * 8 + r8;
      tile[r][c] = Wv[(size_t)(k0 + r) * 1024 + n0 + c];
    }
    __syncthreads();
    if (threadIdx.x < 128) {
      int rr = threadIdx.x & 31;         // n (d_out) within tile
      int k16 = (threadIdx.x >> 5) & 3;  // 8-half group within k0
      half8 h;
      for (int kk = 0; kk < 8; ++kk) h[kk] = (_Float16)tile[k16 * 8 + kk][rr];
      int n_row = n0 + rr;
      size_t chunk = ((size_t)(n_row >> 4) * 32 + (k0 >> 5)) * 64 + (k16 << 4) + (n_row & 15);
      *(half8*)(Wvtp + chunk * 8) = h;
    }
  }
}

// ---------------- shared GEMM core, BK=64 (2 kb-blocks per barrier) ----------
// C[128x128] += A~ * B~^T, both packed. kbA/kbB = K/32 of the packed matrix;
// tA0/tB0 = starting 16-row tile; kPeriods = K-extent/64.
__device__ __forceinline__ void gemm_core(const _Float16* __restrict__ Ap, int kbA, int tA0,
                                          const _Float16* __restrict__ Bp, int kbB, int tB0,
                                          int kPeriods, _Float16* sA, _Float16* sB,
                                          floatx4 acc[4][4]) {
  int tid = threadIdx.x;
  int lane = tid & 63, wave = tid >> 6;
  int wm = (wave >> 1) << 6, wn = (wave & 1) << 6;
  const _Float16* gA0 = Ap + ((size_t)(tA0 + 2 * wave) * kbA) * 512 + lane * 8;
  const _Float16* gA1 = Ap + ((size_t)(tA0 + 2 * wave + 1) * kbA) * 512 + lane * 8;
  const _Float16* gB0 = Bp + ((size_t)(tB0 + 2 * wave) * kbB) * 512 + lane * 8;
  const _Float16* gB1 = Bp + ((size_t)(tB0 + 2 * wave + 1) * kbB) * 512 + lane * 8;
  _Float16* lA = sA + wave * 2048;  // slots 4w..4w+3
  _Float16* lB = sB + wave * 2048;
  int ta = wm >> 4, tb = wn >> 4, lo = lane * 8;

  for (int kt = 0; kt < kPeriods; ++kt) {
    size_t kb = (size_t)kt * 1024;  // 2 consecutive 1KB blocks per tile
    __syncthreads();
    load_lds16(gA0 + kb, lA);
    load_lds16(gA0 + kb + 512, lA + 512);
    load_lds16(gA1 + kb, lA + 1024);
    load_lds16(gA1 + kb + 512, lA + 1536);
    load_lds16(gB0 + kb, lB);
    load_lds16(gB0 + kb + 512, lB + 512);
    load_lds16(gB1 + kb, lB + 1024);
    load_lds16(gB1 + kb + 512, lB + 1536);
    __syncthreads();
    for (int u = 0; u < 2; ++u) {
      half8 af[4], bf[4];
      for (int i = 0; i < 4; ++i) af[i] = *(const half8*)(sA + (((ta + i) << 1) + u) * 512 + lo);
      for (int j = 0; j < 4; ++j) bf[j] = *(const half8*)(sB + (((tb + j) << 1) + u) * 512 + lo);
      for (int i = 0; i < 4; ++i)
        for (int j = 0; j < 4; ++j)
          acc[i][j] = __builtin_amdgcn_mfma_f32_16x16x32_f16(af[i], bf[j], acc[i][j], 0, 0, 0);
    }
  }
}

// ---------------- Mt = Wk.Wq^T (Mt[e'][e] = sum_f Wk[e',f]Wq[e,f]), packed ----
__global__ void mt_kernel(const _Float16* __restrict__ Wkp, const _Float16* __restrict__ Wqp,
                          _Float16* __restrict__ Mtp) {
  __shared__ __align__(16) _Float16 sA[8192];
  __shared__ __align__(16) _Float16 sB[8192];
  floatx4 acc[4][4];
  for (int i = 0; i < 4; ++i)
    for (int j = 0; j < 4; ++j) acc[i][j] = (floatx4){0.f, 0.f, 0.f, 0.f};
  int m0 = blockIdx.y * 128, n0 = blockIdx.x * 128;  // e', e
  gemm_core(Wkp, 32, m0 >> 4, Wqp, 32, n0 >> 4, 16, sA, sB, acc);
  int lane = threadIdx.x & 63, wave = threadIdx.x >> 6;
  int wm = (wave >> 1) << 6, wn = (wave & 1) << 6;
  int quad = lane >> 4, cl = lane & 15;
  for (int i = 0; i < 4; ++i)
    for (int j = 0; j < 4; ++j)
      for (int rr = 0; rr < 4; ++rr) {
        int row = m0 + wm + i * 16 + quad * 4 + rr;  // e' (packed row dim)
        int col = n0 + wn + j * 16 + cl;             // e  (packed k dim)
        size_t chunk = ((size_t)(row >> 4) * 32 + (col >> 5)) * 64 + (((col >> 3) & 3) << 4) + (row & 15);
        Mtp[chunk * 8 + (col & 7)] = (_Float16)acc[i][j][rr];
      }
}

// ---------------- proj: [XM | V] = X . [Mt | Wvt]^T, packed outputs ----------
// B = Mtp (panels 0..63) stacked with Wvtp (panels 64..127), contiguous.
__global__ void proj_kernel(const _Float16* __restrict__ Xp, const _Float16* __restrict__ Bp,
                            _Float16* __restrict__ XMp, _Float16* __restrict__ Vtp) {
  __shared__ __align__(16) _Float16 sA[8192];
  __shared__ __align__(16) _Float16 sB[8192];
  floatx4 acc[4][4];
  for (int i = 0; i < 4; ++i)
    for (int j = 0; j < 4; ++j) acc[i][j] = (floatx4){0.f, 0.f, 0.f, 0.f};
  int m0 = blockIdx.y * 128, n0 = blockIdx.x * 128;
  gemm_core(Xp, 32, m0 >> 4, Bp, 32, n0 >> 4, 16, sA, sB, acc);
  int lane = threadIdx.x & 63, wave = threadIdx.x >> 6;
  int wm = (wave >> 1) << 6, wn = (wave & 1) << 6;
  int quad = lane >> 4, cl = lane & 15;
  int which = n0 >> 10;  // 0=XM 1=V
  int colbase = (n0 & 1023) + wn;
  for (int i = 0; i < 4; ++i)
    for (int j = 0; j < 4; ++j)
      for (int rr = 0; rr < 4; ++rr) {
        int row_g = m0 + wm + i * 16 + quad * 4 + rr;  // 0..8191
        int col = colbase + j * 16 + cl;               // e' or d
        _Float16 val = (_Float16)acc[i][j][rr];
        int b = row_g >> 11, t = row_g & 2047;
        if (which == 1) {
          // packed Vt[d][t]: row dim = d (col), k dim = t
          size_t chunk = ((size_t)(col >> 4) * 64 + (t >> 5)) * 64 + (((t >> 3) & 3) << 4) + (col & 15);
          Vtp[(size_t)b * 2097152 + chunk * 8 + (t & 7)] = val;
        } else {
          size_t chunk = ((size_t)(t >> 4) * 32 + (col >> 5)) * 64 + (((col >> 3) & 3) << 4) + (t & 15);
          XMp[(size_t)b * 2097152 + chunk * 8 + (col & 7)] = val;
        }
      }
}

// ---------------- scores: S PACKED = XM.X^T / 32, lower tiles only -----------
__global__ void qk_kernel(const _Float16* __restrict__ XMp, const _Float16* __restrict__ Xp,
                          _Float16* __restrict__ S) {
  __shared__ __align__(16) _Float16 sA[8192];
  __shared__ __align__(16) _Float16 sB[8192];
  int p = blockIdx.x, b = blockIdx.y;
  int ti = 0;
  while ((ti + 1) * (ti + 2) / 2 <= p) ++ti;
  int tj = p - ti * (ti + 1) / 2;
  const _Float16* Ab = XMp + (size_t)b * 2097152;
  const _Float16* Bb = Xp + (size_t)b * 2097152;  // batch b = panels b*128..
  _Float16* Sb = S + (size_t)b * 4194304;
  floatx4 acc[4][4];
  for (int i = 0; i < 4; ++i)
    for (int j = 0; j < 4; ++j) acc[i][j] = (floatx4){0.f, 0.f, 0.f, 0.f};
  gemm_core(Ab, 32, ti * 8, Bb, 32, tj * 8, 16, sA, sB, acc);
  int lane = threadIdx.x & 63, wave = threadIdx.x >> 6;
  int wm = (wave >> 1) << 6, wn = (wave & 1) << 6;
  int quad = lane >> 4, cl = lane & 15;
  for (int i = 0; i < 4; ++i)
    for (int j = 0; j < 4; ++j)
      for (int rr = 0; rr < 4; ++rr) {
        int row = ti * 128 + wm + i * 16 + quad * 4 + rr;  // t
        int col = tj * 128 + wn + j * 16 + cl;             // s
        float val = acc[i][j][rr] * 0.03125f;  // 1/sqrt(1024)
        if (col > row) val = -INFINITY;        // causal mask (diagonal tiles)
        size_t chunk = ((size_t)(row >> 4) * 64 + (col >> 5)) * 64 + (((col >> 3) & 3) << 4) + (row & 15);
        Sb[chunk * 8 + (col & 7)] = (_Float16)val;
      }
}

// ---------------- softmax over packed S, in place, 16-row panel per block ----
__global__ void softmax_kernel(_Float16* __restrict__ S) {
  __shared__ float redm[4][16];
  __shared__ float reds[4][16];
  int p = blockIdx.x, b = blockIdx.y;  // panel, batch
  _Float16* panel = S + (size_t)b * 4194304 + (size_t)p * 32768;  // 64 kb * 512 halves
  int nkb = ((p >> 3) + 1) * 4;  // valid 32-col blocks for rows in this panel
  int tid = threadIdx.x, lane = tid & 63, w = tid >> 6;
  int row = lane & 15;

  half8 v[16];
  float mx = -INFINITY;
  for (int it = 0; it < 16; ++it) {
    int kb = w + it * 4;
    if (kb < nkb) {
      v[it] = *(const half8*)(panel + (size_t)kb * 512 + lane * 8);
      for (int e = 0; e < 8; ++e) mx = fmaxf(mx, (float)v[it][e]);
    }
  }
  mx = fmaxf(mx, __shfl_xor(mx, 16, 64));
  mx = fmaxf(mx, __shfl_xor(mx, 32, 64));
  if (lane < 16) redm[w][lane] = mx;
  __syncthreads();
  mx = fmaxf(fmaxf(redm[0][row], redm[1][row]), fmaxf(redm[2][row], redm[3][row]));

  float sum = 0.f;
  for (int it = 0; it < 16; ++it) {
    int kb = w + it * 4;
    if (kb < nkb) {
      for (int e = 0; e < 8; ++e) {
        float ev = __expf((float)v[it][e] - mx);  // exp(-inf)=0 handles mask
        v[it][e] = (_Float16)ev;
        sum += ev;
      }
    }
  }
  sum += __shfl_xor(sum, 16, 64);
  sum += __shfl_xor(sum, 32, 64);
  if (lane < 16) reds[w][lane] = sum;
  __syncthreads();
  sum = reds[0][row] + reds[1][row] + reds[2][row] + reds[3][row];
  float inv = 1.0f / sum;

  for (int it = 0; it < 16; ++it) {
    int kb = w + it * 4;
    if (kb < nkb) {
      half8 h;
      for (int e = 0; e < 8; ++e) h[e] = (_Float16)((float)v[it][e] * inv);
      *(half8*)(panel + (size_t)kb * 512 + lane * 8) = h;
    }
  }
}

// ---------------- O = P.Vtp^T, fp32 row-major out ----------------
// blockIdx.y remapped so pairs (ti, 15-ti) balance the causal K-loop lengths.
__global__ void pv_kernel(const _Float16* __restrict__ P, const _Float16* __restrict__ Vtp,
                          float* __restrict__ out) {
  __shared__ __align__(16) _Float16 sA[8192];
  __shared__ __align__(16) _Float16 sB[8192];
  int n0 = blockIdx.x * 128, b = blockIdx.z;
  int y = blockIdx.y;
  int ti = (y & 1) ? (15 - (y >> 1)) : (y >> 1);
  const _Float16* Pb = P + (size_t)b * 4194304;
  const _Float16* Vb = Vtp + (size_t)b * 2097152;
  floatx4 acc[4][4];
  for (int i = 0; i < 4; ++i)
    for (int j = 0; j < 4; ++j) acc[i][j] = (floatx4){0.f, 0.f, 0.f, 0.f};
  gemm_core(Pb, 64, ti * 8, Vb, 64, n0 >> 4, (ti + 1) * 2, sA, sB, acc);  // causal k-limit
  int lane = threadIdx.x & 63, wave = threadIdx.x >> 6;
  int wm = (wave >> 1) << 6, wn = (wave & 1) << 6;
  int quad = lane >> 4, cl = lane & 15;
  for (int i = 0; i < 4; ++i)
    for (int j = 0; j < 4; ++j)
      for (int rr = 0; rr < 4; ++rr) {
        int row = ti * 128 + wm + i * 16 + quad * 4 + rr;  // t
        int col = n0 + wn + j * 16 + cl;                   // d
        float v = acc[i][j][rr];
        out[((size_t)b * 2048 + row) * 1024 + col] = rintf(v * 10000.f) * 1e-4f;
      }
}

extern "C" void kernel_launch(void* const* d_in, const int* in_sizes, int n_in,
                              void* d_out, int out_size, void* d_ws, size_t ws_size,
                              hipStream_t stream) {
  const float* emb = (const float*)d_in[0];
  const float* Wk = (const float*)d_in[1];
  const float* Wq = (const float*)d_in[2];
  const float* Wv = (const float*)d_in[3];
  float* out = (float*)d_out;

  // Layout (fixed from round 7: Mtp and Wvtp are contiguous [Mt|Wvt] and XMp
  // lives strictly AFTER them — round 7 had Wvt aliased onto XMp's region).
  _Float16* ws = (_Float16*)d_ws;
  _Float16* Xp   = ws;                           //  8M halves (packed X)
  _Float16* Wqp  = Xp + (size_t)8192 * 1024;     //  1M (packed Wq rows, k=f)
  _Float16* Wkp  = Wqp + (size_t)1024 * 1024;    //  1M (packed Wk rows, k=f)
  _Float16* Mtp  = Wkp + (size_t)1024 * 1024;    //  1M (packed Wk.Wq^T) — proj B panels 0..63
  _Float16* Wvtp = Mtp + (size_t)1024 * 1024;    //  1M (packed Wv^T)   — proj B panels 64..127
  _Float16* XMp  = Wvtp + (size_t)1024 * 1024;   //  8M (packed XM)
  _Float16* Vtp  = XMp + (size_t)8192 * 1024;    //  8M (packed Vt[d][t])
  _Float16* S    = Vtp + (size_t)8192 * 1024;    // 16M (packed scores; becomes P in place)

  prep_kernel<<<1664, 256, 0, stream>>>(emb, Wq, Wk, Wv, Xp, Wqp, Wkp, Wvtp);
  mt_kernel<<<dim3(8, 8), 256, 0, stream>>>(Wkp, Wqp, Mtp);
  proj_kernel<<<dim3(16, 64), 256, 0, stream>>>(Xp, Mtp, XMp, Vtp);
  qk_kernel<<<dim3(136, 4), 256, 0, stream>>>(XMp, Xp, S);
  softmax_kernel<<<dim3(128, 4), 256, 0, stream>>>(S);
  pv_kernel<<<dim3(8, 16, 4), 256, 0, stream>>>(S, Vtp, out);
}